// Round 15
// baseline (76.347 us; speedup 1.0000x reference)
//
#include <hip/hip_runtime.h>
#include <hip/hip_bf16.h>
#include <stdint.h>

// Problem: B=16, S=1024, IN=1024, OUT=1024.
// Reference collapses: softmax row-sums are exactly 1 (key mask always has >=1
// live column), so out = leaky_relu(xs @ (Wlin@Wv)^T + (Wlin@bv + blin)).
//
// Round 15: main_mb upgraded to a 3-buffer ring with ONE barrier per K-tile
// (stage T+2 after the top barrier; all tile-T ds_reads provably retired
// before any wave passes barrier T+1 -> writing buf[(T+2)%3] is race-free).
// Counted vmcnt(3) per tile (never 0 until tail). Pipeline back to round-10
// shape: prep0 -> prep1 (wcomb || conversion) -> main.

#define M_TOT 16384   // B*S
#define KDIM  1024
#define NDIM  1024
#define NKT   32      // K-tiles of BK=32

typedef __attribute__((ext_vector_type(8))) short bf16x8;
typedef __attribute__((ext_vector_type(4))) float f32x4;
typedef __attribute__((ext_vector_type(4))) unsigned short u16x4;
typedef __attribute__((ext_vector_type(8))) unsigned short u16x8;

static __device__ __forceinline__ unsigned short f2bf(float f) {
    union { float f; unsigned int u; } v; v.f = f;
    unsigned int u = v.u;
    return (unsigned short)((u + 0x7fffu + ((u >> 16) & 1u)) >> 16);  // RNE
}

static __device__ __forceinline__ u16x8 pack8(float4 a, float4 b) {
    u16x8 p = { f2bf(a.x), f2bf(a.y), f2bf(a.z), f2bf(a.w),
                f2bf(b.x), f2bf(b.y), f2bf(b.z), f2bf(b.w) };
    return p;
}

static __device__ __forceinline__ void gload16(const void* g, void* l) {
    __builtin_amdgcn_global_load_lds(
        (__attribute__((address_space(1))) void*)(g),
        (__attribute__((address_space(3))) void*)(l), 16, 0, 0);
}

// Involutive byte-swizzle for 128B-line LDS tiles: XOR line bits (7-9) into
// 16B-slot bits (4-6). Measured 0 bank conflicts (rounds 10-14).
static __device__ __forceinline__ int swz128(int p) {
    return p ^ (((p >> 7) & 7) << 4);
}

// ---------------------------------------------------------------------------
// prep0: [0,256) transpose Wv[d][i] -> Wvt[i][d] bf16 (64x64 tiles, padded
//        fp32 LDS); [256,512) Wlin -> Wlb bf16; [512,768) bias fold.
// ---------------------------------------------------------------------------
__global__ __launch_bounds__(256) void prep0_kernel(
    const float* __restrict__ Wv, const float* __restrict__ Wlin,
    const float* __restrict__ bv, const float* __restrict__ blin,
    unsigned short* __restrict__ Wvt, unsigned short* __restrict__ Wlb,
    float* __restrict__ bcomb) {
    __shared__ float Tl[64 * 65];
    const int bid = blockIdx.x;
    const int t = threadIdx.x;

    if (bid < 256) {
        const int dt = bid >> 4;
        const int it = bid & 15;
        const int r = t >> 2;
        const int c0 = (t & 3) * 16;
        #pragma unroll
        for (int u = 0; u < 4; ++u) {
            float4 v = *(const float4*)&Wv[((size_t)(dt * 64 + r)) * NDIM + it * 64 + c0 + 4 * u];
            Tl[r * 65 + c0 + 4 * u + 0] = v.x;
            Tl[r * 65 + c0 + 4 * u + 1] = v.y;
            Tl[r * 65 + c0 + 4 * u + 2] = v.z;
            Tl[r * 65 + c0 + 4 * u + 3] = v.w;
        }
        __syncthreads();
        const int i = t >> 2;
        const int dq = (t & 3) * 16;
        float v[16];
        #pragma unroll
        for (int u = 0; u < 16; ++u) v[u] = Tl[(dq + u) * 65 + i];
        u16x8 p0 = { f2bf(v[0]), f2bf(v[1]), f2bf(v[2]), f2bf(v[3]),
                     f2bf(v[4]), f2bf(v[5]), f2bf(v[6]), f2bf(v[7]) };
        u16x8 p1 = { f2bf(v[8]), f2bf(v[9]), f2bf(v[10]), f2bf(v[11]),
                     f2bf(v[12]), f2bf(v[13]), f2bf(v[14]), f2bf(v[15]) };
        unsigned short* dst = &Wvt[((size_t)(it * 64 + i)) * KDIM + dt * 64 + dq];
        *(u16x8*)dst = p0;
        *(u16x8*)(dst + 8) = p1;
    } else if (bid < 512) {
        const size_t idx = (((size_t)(bid - 256)) * 256 + t) * 16;
        float4 a = *(const float4*)&Wlin[idx];
        float4 b = *(const float4*)&Wlin[idx + 4];
        float4 c = *(const float4*)&Wlin[idx + 8];
        float4 d = *(const float4*)&Wlin[idx + 12];
        *(u16x8*)&Wlb[idx] = pack8(a, b);
        *(u16x8*)&Wlb[idx + 8] = pack8(c, d);
    } else {
        const int wave = t >> 6, lane = t & 63;
        const int o = (bid - 512) * 4 + wave;
        float s = 0.f;
        for (int d = lane; d < KDIM; d += 64) s += Wlin[o * KDIM + d] * bv[d];
        #pragma unroll
        for (int off = 32; off > 0; off >>= 1) s += __shfl_down(s, off, 64);
        if (lane == 0) bcomb[o] = s + blin[o];
    }
}

// ---------------------------------------------------------------------------
// prep1: [0,256): Wc[o][i] = sum_d Wlb[o][d]*Wvt[i][d] (64x64 tiles);
//        [256,2304): Xb = bf16(xs). The GEMM hides under the conversion.
// ---------------------------------------------------------------------------
__global__ __launch_bounds__(256) void prep1_kernel(
    const unsigned short* __restrict__ Wlb, const unsigned short* __restrict__ Wvt,
    const float* __restrict__ xs, unsigned short* __restrict__ Wc,
    unsigned short* __restrict__ Xb) {
    __shared__ unsigned short As[64 * 32];
    __shared__ unsigned short Bs[64 * 32];
    const int bid = blockIdx.x;
    const int t = threadIdx.x;

    if (bid >= 256) {
        const size_t base = (((size_t)(bid - 256)) * 256 + t) * 8;
        #pragma unroll
        for (int itr = 0; itr < 4; ++itr) {
            const size_t idx = base + (size_t)itr * (size_t)(2048 * 256 * 8);
            float4 a = *(const float4*)&xs[idx];
            float4 b = *(const float4*)&xs[idx + 4];
            *(u16x8*)&Xb[idx] = pack8(a, b);
        }
        return;
    }

    const int ot = bid >> 4;
    const int it = bid & 15;
    const int w = t >> 6, l = t & 63;
    const int wr = (w >> 1) * 32, wc = (w & 1) * 32;
    const int lr = l & 15, lk = l >> 4;

    f32x4 acc[2][2] = {};

    const unsigned short* gA = &Wlb[((size_t)(ot * 64 + (t >> 2))) * KDIM + (t & 3) * 8];
    const unsigned short* gB = &Wvt[((size_t)(it * 64 + (t >> 2))) * KDIM + (t & 3) * 8];
    unsigned short* lA = &As[w * 512];
    unsigned short* lB = &Bs[w * 512];

    for (int kt = 0; kt < KDIM / 32; ++kt) {
        gload16(gA + kt * 32, lA);
        gload16(gB + kt * 32, lB);
        __syncthreads();
        bf16x8 af[2], bfr[2];
        #pragma unroll
        for (int fi = 0; fi < 2; ++fi)
            af[fi] = *(bf16x8*)&As[(wr + fi * 16 + lr) * 32 + lk * 8];
        #pragma unroll
        for (int fj = 0; fj < 2; ++fj)
            bfr[fj] = *(bf16x8*)&Bs[(wc + fj * 16 + lr) * 32 + lk * 8];
        #pragma unroll
        for (int fi = 0; fi < 2; ++fi)
            #pragma unroll
            for (int fj = 0; fj < 2; ++fj)
                acc[fi][fj] = __builtin_amdgcn_mfma_f32_16x16x32_bf16(
                    af[fi], bfr[fj], acc[fi][fj], 0, 0, 0);
        __syncthreads();
    }
    #pragma unroll
    for (int fi = 0; fi < 2; ++fi)
        #pragma unroll
        for (int fj = 0; fj < 2; ++fj)
            #pragma unroll
            for (int r = 0; r < 4; ++r) {
                const int o = ot * 64 + wr + fi * 16 + lk * 4 + r;
                const int i = it * 64 + wc + fj * 16 + lr;
                Wc[(size_t)o * KDIM + i] = f2bf(acc[fi][fj][r]);
            }
}

// ---------------------------------------------------------------------------
// main_mb3: out = leaky(Xb @ Wc^T + bcomb). Multi-block + ring-3.
// BM=256, BN=128, BK=32, 8 waves (4Mx2N), per-wave 64x64 = acc[4][4].
// LDS 73728 = 3 bufs x (A 16KB + B 8KB), row-pair swz128 (0-conflict).
// Per tile: counted vmcnt(3) -> ONE s_barrier -> stage T+2 into ring slot
// (race-free: tile-T ds_reads retired before any wave passes barrier T+1)
// -> frag reads -> 16 MFMA (setprio). 2 blocks/CU, grid 512, XCD swizzle.
// ---------------------------------------------------------------------------
__global__ __launch_bounds__(512, 4) void main_mb3(
    const unsigned short* __restrict__ Xb, const unsigned short* __restrict__ Wc,
    const float* __restrict__ bcomb, float* __restrict__ out) {
    extern __shared__ char lds[];  // 73728
    const int tid = threadIdx.x;
    const int w = tid >> 6, l = tid & 63;
    const int wm = w >> 1, wn = w & 1;
    const int lr = l & 15, lk = l >> 4;

    // XCD swizzle (512 % 8 == 0, bijective): 64 consecutive per XCD.
    const int swzb = ((blockIdx.x & 7) << 6) | (blockIdx.x >> 3);
    const int mt = swzb >> 3, nt = swzb & 7;

    // reader byte offsets: row r, k-slot lk -> logical byte
    // P = (r>>1)*128 + (r&1)*64 + lk*16; physical = swz128(P).
    int aoff[4], boff[4];
    #pragma unroll
    for (int fi = 0; fi < 4; ++fi) {
        const int r = wm * 64 + fi * 16 + lr;
        aoff[fi] = swz128(((r >> 1) << 7) | ((r & 1) << 6) | (lk << 4));
    }
    #pragma unroll
    for (int fj = 0; fj < 4; ++fj) {
        const int r = wn * 64 + fj * 16 + lr;
        boff[fj] = 16384 + swz128(((r >> 1) << 7) | ((r & 1) << 6) | (lk << 4));
    }

    // staging: linear LDS dests, pre-swizzled global sources (rule #21).
    const char* srcA[2];
    #pragma unroll
    for (int c = 0; c < 2; ++c) {
        const int q = c * 8192 + tid * 16;
        const int p = swz128(q);
        const int r = ((p >> 7) << 1) | ((p >> 6) & 1);   // 0..255
        srcA[c] = (const char*)Xb + ((size_t)(mt * 256 + r)) * 2048 + (p & 63);
    }
    const char* srcB;
    {
        const int q = tid * 16;
        const int p = swz128(q);
        const int r = ((p >> 7) << 1) | ((p >> 6) & 1);   // 0..127
        srcB = (const char*)Wc + ((size_t)(nt * 128 + r)) * 2048 + (p & 63);
    }
    const int ldsAw = w * 1024;         // + c*8192 within A region
    const int ldsBw = 16384 + w * 1024;

    f32x4 acc[4][4] = {};

#define STAGE(TT, OFF)                                                         \
    do {                                                                       \
        gload16(srcA[0] + (size_t)(TT) * 64, lds + (OFF) + ldsAw);             \
        gload16(srcA[1] + (size_t)(TT) * 64, lds + (OFF) + 8192 + ldsAw);      \
        gload16(srcB + (size_t)(TT) * 64, lds + (OFF) + ldsBw);                \
    } while (0)

    // prologue: stage tiles 0,1 into ring slots 0,1
    STAGE(0, 0);
    STAGE(1, 24576);

    int oc = 0, on = 24576, ol = 49152;   // tile kt / kt+1 / kt+2 ring slots

    for (int kt = 0; kt < NKT; ++kt) {
        if (kt < NKT - 1)
            asm volatile("s_waitcnt vmcnt(3)" ::: "memory");  // tile kt landed
        else
            asm volatile("s_waitcnt vmcnt(0)" ::: "memory");
        __builtin_amdgcn_s_barrier();

        if (kt + 2 < NKT) STAGE(kt + 2, ol);

        const char* cbuf = lds + oc;
        bf16x8 af[4], bfr[4];
        #pragma unroll
        for (int fi = 0; fi < 4; ++fi)
            af[fi] = *(const bf16x8*)(cbuf + aoff[fi]);
        #pragma unroll
        for (int fj = 0; fj < 4; ++fj)
            bfr[fj] = *(const bf16x8*)(cbuf + boff[fj]);

        __builtin_amdgcn_s_setprio(1);
        #pragma unroll
        for (int fi = 0; fi < 4; ++fi)
            #pragma unroll
            for (int fj = 0; fj < 4; ++fj)
                acc[fi][fj] = __builtin_amdgcn_mfma_f32_16x16x32_bf16(
                    af[fi], bfr[fj], acc[fi][fj], 0, 0, 0);
        __builtin_amdgcn_s_setprio(0);

        const int tmp = oc; oc = on; on = ol; ol = tmp;  // rotate ring
    }
#undef STAGE

    // epilogue: + bias, leaky_relu, fp32 store
    #pragma unroll
    for (int fi = 0; fi < 4; ++fi)
        #pragma unroll
        for (int fj = 0; fj < 4; ++fj) {
            const int col = nt * 128 + wn * 64 + fj * 16 + lr;
            const float b = bcomb[col];
            #pragma unroll
            for (int r = 0; r < 4; ++r) {
                const int row = mt * 256 + wm * 64 + fi * 16 + lk * 4 + r;
                float v = acc[fi][fj][r] + b;
                out[(size_t)row * NDIM + col] = v >= 0.f ? v : 0.01f * v;
            }
        }
}

// ---------------------------------------------------------------------------
// Fallback main GEMM (fused fp32->bf16 A path, 128x128) if ws is too small.
// ---------------------------------------------------------------------------
__global__ __launch_bounds__(256) void main_gemm_f32(
    const float* __restrict__ X, const unsigned short* __restrict__ Wc,
    const float* __restrict__ bcomb, float* __restrict__ out) {
    __shared__ unsigned short As[128 * 32];
    __shared__ unsigned short Bs[128 * 32];
    const int t = threadIdx.x;
    const int nt = blockIdx.x & 7;
    const int mt = blockIdx.x >> 3;
    const int w = t >> 6, l = t & 63;
    const int wr = (w >> 1) * 64, wcc = (w & 1) * 64;
    const int lr = l & 15, lk = l >> 4;

    f32x4 acc[4][4] = {};

    const int arow = t >> 3;
    const int akq = t & 7;
    const int brow = t >> 2;
    const int bc4 = t & 3;

    for (int kt = 0; kt < KDIM / 32; ++kt) {
        float4 av[4];
        #pragma unroll
        for (int j = 0; j < 4; ++j) {
            const int row = j * 32 + arow;
            av[j] = *(const float4*)&X[(mt * 128 + row) * KDIM + kt * 32 + akq * 4];
        }
        __syncthreads();
        #pragma unroll
        for (int j = 0; j < 4; ++j) {
            const int row = j * 32 + arow;
            u16x4 p = { f2bf(av[j].x), f2bf(av[j].y), f2bf(av[j].z), f2bf(av[j].w) };
            *(u16x4*)&As[row * 32 + akq * 4] = p;
        }
        #pragma unroll
        for (int j = 0; j < 2; ++j) {
            const int row = j * 64 + brow;
            const unsigned short* g = &Wc[(nt * 128 + row) * KDIM + kt * 32 + bc4 * 8];
            unsigned short* ldst = &Bs[(j * 256 + w * 64) * 8];
            gload16(g, ldst);
        }
        __syncthreads();
        bf16x8 af[4], bfr[4];
        #pragma unroll
        for (int fi = 0; fi < 4; ++fi)
            af[fi] = *(bf16x8*)&As[(wr + fi * 16 + lr) * 32 + lk * 8];
        #pragma unroll
        for (int fj = 0; fj < 4; ++fj)
            bfr[fj] = *(bf16x8*)&Bs[(wcc + fj * 16 + lr) * 32 + lk * 8];
        #pragma unroll
        for (int fi = 0; fi < 4; ++fi)
            #pragma unroll
            for (int fj = 0; fj < 4; ++fj)
                acc[fi][fj] = __builtin_amdgcn_mfma_f32_16x16x32_bf16(
                    af[fi], bfr[fj], acc[fi][fj], 0, 0, 0);
    }

    #pragma unroll
    for (int fi = 0; fi < 4; ++fi)
        #pragma unroll
        for (int fj = 0; fj < 4; ++fj) {
            const int col = nt * 128 + wcc + fj * 16 + lr;
            const float b = bcomb[col];
            #pragma unroll
            for (int r = 0; r < 4; ++r) {
                const int row = mt * 128 + wr + fi * 16 + lk * 4 + r;
                float v = acc[fi][fj][r] + b;
                out[row * NDIM + col] = v >= 0.f ? v : 0.01f * v;
            }
        }
}

extern "C" void kernel_launch(void* const* d_in, const int* in_sizes, int n_in,
                              void* d_out, int out_size, void* d_ws, size_t ws_size,
                              hipStream_t stream) {
    const float* xs   = (const float*)d_in[0];
    // d_in[1] mask unused: softmax row-sums are exactly 1.
    const float* Wv   = (const float*)d_in[6];
    const float* bv   = (const float*)d_in[7];
    const float* Wlin = (const float*)d_in[8];
    const float* blin = (const float*)d_in[9];

    unsigned short* Wc = (unsigned short*)d_ws;                         // 2 MB
    float* bcomb = (float*)((char*)d_ws + 2097152);                     // 4 KB
    unsigned short* Xb = (unsigned short*)((char*)d_ws + 2101248);      // 32 MB
    float* out = (float*)d_out;

    // transient scratch in d_out (64 MB, fully overwritten by the final GEMM)
    unsigned short* Wvt = (unsigned short*)d_out;                       // 2 MB
    unsigned short* Wlb = (unsigned short*)((char*)d_out + 2097152);    // 2 MB

    const size_t NEED = 2101248 + (size_t)M_TOT * KDIM * 2;
    hipLaunchKernelGGL(prep0_kernel, dim3(768), dim3(256), 0, stream,
                       Wv, Wlin, bv, blin, Wvt, Wlb, bcomb);
    if (ws_size >= NEED) {
        (void)hipFuncSetAttribute((const void*)main_mb3,
                                  hipFuncAttributeMaxDynamicSharedMemorySize,
                                  73728);
        hipLaunchKernelGGL(prep1_kernel, dim3(256 + 2048), dim3(256), 0, stream,
                           Wlb, Wvt, xs, Wc, Xb);
        hipLaunchKernelGGL(main_mb3, dim3(512), dim3(512), 73728, stream,
                           Xb, Wc, bcomb, out);
    } else {
        hipLaunchKernelGGL(prep1_kernel, dim3(256), dim3(256), 0, stream,
                           Wlb, Wvt, xs, Wc, Xb);
        hipLaunchKernelGGL(main_gemm_f32, dim3((M_TOT / 128) * (NDIM / 128)),
                           dim3(256), 0, stream, xs, Wc, bcomb, out);
    }
}

// Round 16
// 73.646 us; speedup vs baseline: 1.0367x; 1.0367x over previous
//
#include <hip/hip_runtime.h>
#include <hip/hip_bf16.h>
#include <stdint.h>

// Problem: B=16, S=1024, IN=1024, OUT=1024.
// Reference collapses: softmax row-sums are exactly 1 (key mask always has >=1
// live column), so out = leaky_relu(xs @ (Wlin@Wv)^T + (Wlin@bv + blin)).
//
// Round 16: READ-side A conversion. Round-14's proven multi-block structure
// (44.3us main) kept intact; A staged as raw fp32 via global_load_lds (pure
// DMA, no write-side cvt - the failure mode of all 6 prior fused attempts),
// converted per-fragment at read time with v_cvt_pk_bf16_f32 (VALU co-issues
// with MFMA, m114). Conversion pass (prep1/Xb, ~20us + 96MB traffic) deleted.
// Pipeline: prep0 (transpose/bias) -> wcomb -> main_f32a.

#define M_TOT 16384   // B*S
#define KDIM  1024
#define NDIM  1024
#define NKT   32      // K-tiles of BK=32

typedef __attribute__((ext_vector_type(8))) short bf16x8;
typedef __attribute__((ext_vector_type(4))) float f32x4;
typedef __attribute__((ext_vector_type(4))) unsigned short u16x4;
typedef __attribute__((ext_vector_type(8))) unsigned short u16x8;
typedef __attribute__((ext_vector_type(4))) unsigned int u32x4;

static __device__ __forceinline__ unsigned short f2bf(float f) {
    union { float f; unsigned int u; } v; v.f = f;
    unsigned int u = v.u;
    return (unsigned short)((u + 0x7fffu + ((u >> 16) & 1u)) >> 16);  // RNE
}

static __device__ __forceinline__ u16x8 pack8(float4 a, float4 b) {
    u16x8 p = { f2bf(a.x), f2bf(a.y), f2bf(a.z), f2bf(a.w),
                f2bf(b.x), f2bf(b.y), f2bf(b.z), f2bf(b.w) };
    return p;
}

// HW packed fp32->bf16 (RNE), 2 elems/instr.
static __device__ __forceinline__ unsigned int cvtpk(float lo, float hi) {
    unsigned int r;
    asm("v_cvt_pk_bf16_f32 %0, %1, %2" : "=v"(r) : "v"(lo), "v"(hi));
    return r;
}

static __device__ __forceinline__ void gload16(const void* g, void* l) {
    __builtin_amdgcn_global_load_lds(
        (__attribute__((address_space(1))) void*)(g),
        (__attribute__((address_space(3))) void*)(l), 16, 0, 0);
}

// Involutive byte-swizzle for 128B-line LDS tiles: XOR line bits (7-9) into
// 16B-slot bits (4-6). Measured 0 bank conflicts (rounds 10-15).
static __device__ __forceinline__ int swz128(int p) {
    return p ^ (((p >> 7) & 7) << 4);
}

// ---------------------------------------------------------------------------
// prep0: [0,256) transpose Wv[d][i] -> Wvt[i][d] bf16 (64x64 tiles, padded
//        fp32 LDS); [256,512) Wlin -> Wlb bf16; [512,768) bias fold.
// ---------------------------------------------------------------------------
__global__ __launch_bounds__(256) void prep0_kernel(
    const float* __restrict__ Wv, const float* __restrict__ Wlin,
    const float* __restrict__ bv, const float* __restrict__ blin,
    unsigned short* __restrict__ Wvt, unsigned short* __restrict__ Wlb,
    float* __restrict__ bcomb) {
    __shared__ float Tl[64 * 65];
    const int bid = blockIdx.x;
    const int t = threadIdx.x;

    if (bid < 256) {
        const int dt = bid >> 4;
        const int it = bid & 15;
        const int r = t >> 2;
        const int c0 = (t & 3) * 16;
        #pragma unroll
        for (int u = 0; u < 4; ++u) {
            float4 v = *(const float4*)&Wv[((size_t)(dt * 64 + r)) * NDIM + it * 64 + c0 + 4 * u];
            Tl[r * 65 + c0 + 4 * u + 0] = v.x;
            Tl[r * 65 + c0 + 4 * u + 1] = v.y;
            Tl[r * 65 + c0 + 4 * u + 2] = v.z;
            Tl[r * 65 + c0 + 4 * u + 3] = v.w;
        }
        __syncthreads();
        const int i = t >> 2;
        const int dq = (t & 3) * 16;
        float v[16];
        #pragma unroll
        for (int u = 0; u < 16; ++u) v[u] = Tl[(dq + u) * 65 + i];
        u16x8 p0 = { f2bf(v[0]), f2bf(v[1]), f2bf(v[2]), f2bf(v[3]),
                     f2bf(v[4]), f2bf(v[5]), f2bf(v[6]), f2bf(v[7]) };
        u16x8 p1 = { f2bf(v[8]), f2bf(v[9]), f2bf(v[10]), f2bf(v[11]),
                     f2bf(v[12]), f2bf(v[13]), f2bf(v[14]), f2bf(v[15]) };
        unsigned short* dst = &Wvt[((size_t)(it * 64 + i)) * KDIM + dt * 64 + dq];
        *(u16x8*)dst = p0;
        *(u16x8*)(dst + 8) = p1;
    } else if (bid < 512) {
        const size_t idx = (((size_t)(bid - 256)) * 256 + t) * 16;
        float4 a = *(const float4*)&Wlin[idx];
        float4 b = *(const float4*)&Wlin[idx + 4];
        float4 c = *(const float4*)&Wlin[idx + 8];
        float4 d = *(const float4*)&Wlin[idx + 12];
        *(u16x8*)&Wlb[idx] = pack8(a, b);
        *(u16x8*)&Wlb[idx + 8] = pack8(c, d);
    } else {
        const int wave = t >> 6, lane = t & 63;
        const int o = (bid - 512) * 4 + wave;
        float s = 0.f;
        for (int d = lane; d < KDIM; d += 64) s += Wlin[o * KDIM + d] * bv[d];
        #pragma unroll
        for (int off = 32; off > 0; off >>= 1) s += __shfl_down(s, off, 64);
        if (lane == 0) bcomb[o] = s + blin[o];
    }
}

// ---------------------------------------------------------------------------
// wcomb: Wc[o][i] = sum_d Wlb[o][d] * Wvt[i][d]. 64x64 tiles, 256 blocks,
// 4 waves (2x2 of 32x32), both operands via global_load_lds.
// ---------------------------------------------------------------------------
__global__ __launch_bounds__(256) void wcomb_kernel(
    const unsigned short* __restrict__ Wlb, const unsigned short* __restrict__ Wvt,
    unsigned short* __restrict__ Wc) {
    __shared__ unsigned short As[64 * 32];
    __shared__ unsigned short Bs[64 * 32];
    const int t = threadIdx.x;
    const int ot = blockIdx.x >> 4;
    const int it = blockIdx.x & 15;
    const int w = t >> 6, l = t & 63;
    const int wr = (w >> 1) * 32, wc = (w & 1) * 32;
    const int lr = l & 15, lk = l >> 4;

    f32x4 acc[2][2] = {};

    const unsigned short* gA = &Wlb[((size_t)(ot * 64 + (t >> 2))) * KDIM + (t & 3) * 8];
    const unsigned short* gB = &Wvt[((size_t)(it * 64 + (t >> 2))) * KDIM + (t & 3) * 8];
    unsigned short* lA = &As[w * 512];
    unsigned short* lB = &Bs[w * 512];

    for (int kt = 0; kt < KDIM / 32; ++kt) {
        gload16(gA + kt * 32, lA);
        gload16(gB + kt * 32, lB);
        __syncthreads();
        bf16x8 af[2], bfr[2];
        #pragma unroll
        for (int fi = 0; fi < 2; ++fi)
            af[fi] = *(bf16x8*)&As[(wr + fi * 16 + lr) * 32 + lk * 8];
        #pragma unroll
        for (int fj = 0; fj < 2; ++fj)
            bfr[fj] = *(bf16x8*)&Bs[(wc + fj * 16 + lr) * 32 + lk * 8];
        #pragma unroll
        for (int fi = 0; fi < 2; ++fi)
            #pragma unroll
            for (int fj = 0; fj < 2; ++fj)
                acc[fi][fj] = __builtin_amdgcn_mfma_f32_16x16x32_bf16(
                    af[fi], bfr[fj], acc[fi][fj], 0, 0, 0);
        __syncthreads();
    }
    #pragma unroll
    for (int fi = 0; fi < 2; ++fi)
        #pragma unroll
        for (int fj = 0; fj < 2; ++fj)
            #pragma unroll
            for (int r = 0; r < 4; ++r) {
                const int o = ot * 64 + wr + fi * 16 + lk * 4 + r;
                const int i = it * 64 + wc + fj * 16 + lr;
                Wc[(size_t)o * KDIM + i] = f2bf(acc[fi][fj][r]);
            }
}

// ---------------------------------------------------------------------------
// main_f32a: out = leaky(bf16(xs) @ Wc^T + bcomb).
// Round-14 structure (proven 44.3us): BM=256, BN=128, BK=32, 8 waves (4Mx2N),
// per-wave 64x64 = acc[4][4], depth-1 counted-vmcnt staging, 2 barriers/tile,
// grid 512 = 2 blocks/CU, bijective XCD swizzle.
// NEW: A region is raw fp32 [256][32] (128B rows, swz128 direct) staged by
// 4 gload_lds/thread; waves convert A-frags at read time via
// v_cvt_pk_bf16_f32 (16 instr/wave/tile, co-issues with MFMA).
// B region bf16 [128][32] row-pair swz128 (unchanged, 0-conflict).
// LDS = 2 slots x (A 32KB + B 8KB) = 80KB -> exactly 2 blocks/CU.
// ---------------------------------------------------------------------------
__global__ __launch_bounds__(512, 4) void main_f32a(
    const float* __restrict__ xs, const unsigned short* __restrict__ Wc,
    const float* __restrict__ bcomb, float* __restrict__ out) {
    extern __shared__ char lds[];  // 81920
    const int tid = threadIdx.x;
    const int w = tid >> 6, l = tid & 63;
    const int wm = w >> 1, wn = w & 1;
    const int lr = l & 15, lk = l >> 4;

    // XCD swizzle (512 % 8 == 0, bijective): 64 consecutive per XCD.
    const int swzb = ((blockIdx.x & 7) << 6) | (blockIdx.x >> 3);
    const int mt = swzb >> 3, nt = swzb & 7;

    // A reader offsets (fp32 rows, 128B natural lines): row r, k-slot lk
    // covers fp32 k in [lk*8, lk*8+8) = 32B at logical (r<<7)|(lk<<5).
    int aoff[4], boff[4];
    #pragma unroll
    for (int fi = 0; fi < 4; ++fi) {
        const int r = wm * 64 + fi * 16 + lr;
        aoff[fi] = swz128((r << 7) | (lk << 5));
    }
    // B reader offsets (bf16 row-pair packing, region base 32768).
    #pragma unroll
    for (int fj = 0; fj < 4; ++fj) {
        const int r = wn * 64 + fj * 16 + lr;
        boff[fj] = 32768 + swz128(((r >> 1) << 7) | ((r & 1) << 6) | (lk << 4));
    }

    // staging: linear LDS dests, pre-swizzled global sources (rule #21).
    // A: 4 chunks of 8KB; thread covers q = c*8192 + tid*16 (16B = 4 fp32).
    const char* srcA[4];
    #pragma unroll
    for (int c = 0; c < 4; ++c) {
        const int q = c * 8192 + tid * 16;
        const int p = swz128(q);
        const int r = p >> 7;            // 0..255
        srcA[c] = (const char*)xs + ((size_t)(mt * 256 + r)) * 4096 + (p & 127);
    }
    // B: 1 chunk of 8KB; q = tid*16, row-pair layout.
    const char* srcB;
    {
        const int q = tid * 16;
        const int p = swz128(q);
        const int r = ((p >> 7) << 1) | ((p >> 6) & 1);   // 0..127
        srcB = (const char*)Wc + ((size_t)(nt * 128 + r)) * 2048 + (p & 63);
    }
    const int ldsw = w * 1024;   // wave-uniform base within each 8KB chunk

    f32x4 acc[4][4] = {};

#define STAGE(TT, SLOT)                                                        \
    do {                                                                       \
        gload16(srcA[0] + (size_t)(TT) * 128, lds + (SLOT) + 0 * 8192 + ldsw); \
        gload16(srcA[1] + (size_t)(TT) * 128, lds + (SLOT) + 1 * 8192 + ldsw); \
        gload16(srcA[2] + (size_t)(TT) * 128, lds + (SLOT) + 2 * 8192 + ldsw); \
        gload16(srcA[3] + (size_t)(TT) * 128, lds + (SLOT) + 3 * 8192 + ldsw); \
        gload16(srcB + (size_t)(TT) * 64, lds + (SLOT) + 32768 + ldsw);        \
    } while (0)

    // prologue: stage tile 0 into slot 0
    STAGE(0, 0);

    for (int kt = 0; kt < NKT; ++kt) {
        const int cur = (kt & 1) * 40960;
        const int nxt = ((kt & 1) ^ 1) * 40960;

        if (kt < NKT - 1) {
            STAGE(kt + 1, nxt);
            asm volatile("s_waitcnt vmcnt(5)" ::: "memory");  // tile kt landed
        } else {
            asm volatile("s_waitcnt vmcnt(0)" ::: "memory");
        }
        __builtin_amdgcn_s_barrier();

        const char* cbuf = lds + cur;

        // A frags: fp32 from LDS -> packed bf16 in regs (v_cvt_pk_bf16_f32)
        bf16x8 af[4], bfr[4];
        #pragma unroll
        for (int fi = 0; fi < 4; ++fi) {
            float4 lo = *(const float4*)(cbuf + aoff[fi]);
            float4 hi = *(const float4*)(cbuf + (aoff[fi] ^ 16));
            u32x4 pw = { cvtpk(lo.x, lo.y), cvtpk(lo.z, lo.w),
                         cvtpk(hi.x, hi.y), cvtpk(hi.z, hi.w) };
            af[fi] = *(bf16x8*)&pw;
        }
        #pragma unroll
        for (int fj = 0; fj < 4; ++fj)
            bfr[fj] = *(const bf16x8*)(cbuf + boff[fj]);

        __builtin_amdgcn_s_setprio(1);
        #pragma unroll
        for (int fi = 0; fi < 4; ++fi)
            #pragma unroll
            for (int fj = 0; fj < 4; ++fj)
                acc[fi][fj] = __builtin_amdgcn_mfma_f32_16x16x32_bf16(
                    af[fi], bfr[fj], acc[fi][fj], 0, 0, 0);
        __builtin_amdgcn_s_setprio(0);

        // end barrier: all this tile's ds_reads retired (compiler lgkm-waits
        // before the MFMAs/cvts) before next iter's STAGE overwrites cur.
        __builtin_amdgcn_s_barrier();
    }
#undef STAGE

    // epilogue: + bias, leaky_relu, fp32 store
    #pragma unroll
    for (int fi = 0; fi < 4; ++fi)
        #pragma unroll
        for (int fj = 0; fj < 4; ++fj) {
            const int col = nt * 128 + wn * 64 + fj * 16 + lr;
            const float b = bcomb[col];
            #pragma unroll
            for (int r = 0; r < 4; ++r) {
                const int row = mt * 256 + wm * 64 + fi * 16 + lk * 4 + r;
                float v = acc[fi][fj][r] + b;
                out[(size_t)row * NDIM + col] = v >= 0.f ? v : 0.01f * v;
            }
        }
}

// ---------------------------------------------------------------------------
// Fallback main GEMM (fused fp32->bf16 A path, 128x128) if ws is too small.
// ---------------------------------------------------------------------------
__global__ __launch_bounds__(256) void main_gemm_f32(
    const float* __restrict__ X, const unsigned short* __restrict__ Wc,
    const float* __restrict__ bcomb, float* __restrict__ out) {
    __shared__ unsigned short As[128 * 32];
    __shared__ unsigned short Bs[128 * 32];
    const int t = threadIdx.x;
    const int nt = blockIdx.x & 7;
    const int mt = blockIdx.x >> 3;
    const int w = t >> 6, l = t & 63;
    const int wr = (w >> 1) * 64, wcc = (w & 1) * 64;
    const int lr = l & 15, lk = l >> 4;

    f32x4 acc[4][4] = {};

    const int arow = t >> 3;
    const int akq = t & 7;
    const int brow = t >> 2;
    const int bc4 = t & 3;

    for (int kt = 0; kt < KDIM / 32; ++kt) {
        float4 av[4];
        #pragma unroll
        for (int j = 0; j < 4; ++j) {
            const int row = j * 32 + arow;
            av[j] = *(const float4*)&X[(mt * 128 + row) * KDIM + kt * 32 + akq * 4];
        }
        __syncthreads();
        #pragma unroll
        for (int j = 0; j < 4; ++j) {
            const int row = j * 32 + arow;
            u16x4 p = { f2bf(av[j].x), f2bf(av[j].y), f2bf(av[j].z), f2bf(av[j].w) };
            *(u16x4*)&As[row * 32 + akq * 4] = p;
        }
        #pragma unroll
        for (int j = 0; j < 2; ++j) {
            const int row = j * 64 + brow;
            const unsigned short* g = &Wc[(nt * 128 + row) * KDIM + kt * 32 + bc4 * 8];
            unsigned short* ldst = &Bs[(j * 256 + w * 64) * 8];
            gload16(g, ldst);
        }
        __syncthreads();
        bf16x8 af[4], bfr[4];
        #pragma unroll
        for (int fi = 0; fi < 4; ++fi)
            af[fi] = *(bf16x8*)&As[(wr + fi * 16 + lr) * 32 + lk * 8];
        #pragma unroll
        for (int fj = 0; fj < 4; ++fj)
            bfr[fj] = *(bf16x8*)&Bs[(wcc + fj * 16 + lr) * 32 + lk * 8];
        #pragma unroll
        for (int fi = 0; fi < 4; ++fi)
            #pragma unroll
            for (int fj = 0; fj < 4; ++fj)
                acc[fi][fj] = __builtin_amdgcn_mfma_f32_16x16x32_bf16(
                    af[fi], bfr[fj], acc[fi][fj], 0, 0, 0);
    }

    #pragma unroll
    for (int fi = 0; fi < 4; ++fi)
        #pragma unroll
        for (int fj = 0; fj < 4; ++fj) {
            const int col = nt * 128 + wcc + fj * 16 + lr;
            const float b = bcomb[col];
            #pragma unroll
            for (int r = 0; r < 4; ++r) {
                const int row = mt * 128 + wr + fi * 16 + lk * 4 + r;
                float v = acc[fi][fj][r] + b;
                out[row * NDIM + col] = v >= 0.f ? v : 0.01f * v;
            }
        }
}

extern "C" void kernel_launch(void* const* d_in, const int* in_sizes, int n_in,
                              void* d_out, int out_size, void* d_ws, size_t ws_size,
                              hipStream_t stream) {
    const float* xs   = (const float*)d_in[0];
    // d_in[1] mask unused: softmax row-sums are exactly 1.
    const float* Wv   = (const float*)d_in[6];
    const float* bv   = (const float*)d_in[7];
    const float* Wlin = (const float*)d_in[8];
    const float* blin = (const float*)d_in[9];

    unsigned short* Wc = (unsigned short*)d_ws;                         // 2 MB
    float* bcomb = (float*)((char*)d_ws + 2097152);                     // 4 KB
    float* out = (float*)d_out;

    // transient scratch in d_out (64 MB, fully overwritten by the final GEMM)
    unsigned short* Wvt = (unsigned short*)d_out;                       // 2 MB
    unsigned short* Wlb = (unsigned short*)((char*)d_out + 2097152);    // 2 MB

    const size_t NEED = 2101248;
    hipLaunchKernelGGL(prep0_kernel, dim3(768), dim3(256), 0, stream,
                       Wv, Wlin, bv, blin, Wvt, Wlb, bcomb);
    hipLaunchKernelGGL(wcomb_kernel, dim3(256), dim3(256), 0, stream,
                       Wlb, Wvt, Wc);
    if (ws_size >= NEED) {
        (void)hipFuncSetAttribute((const void*)main_f32a,
                                  hipFuncAttributeMaxDynamicSharedMemorySize,
                                  81920);
        hipLaunchKernelGGL(main_f32a, dim3(512), dim3(512), 81920, stream,
                           xs, Wc, bcomb, out);
    } else {
        hipLaunchKernelGGL(main_gemm_f32, dim3((M_TOT / 128) * (NDIM / 128)),
                           dim3(256), 0, stream, xs, Wc, bcomb, out);
    }
}